// Round 11
// baseline (41180.142 us; speedup 1.0000x reference)
//
#include <hip/hip_runtime.h>

#define Bn 4096
#define Tn 256
#define NZ 64
#define Hn 512
#define INn 68
#define DPRv 24.0f
#define MB 32
#define NTHREADS 1024
#define NBLK 256
#define NPAIR 128

#define NGRP 37
// gate region: 16 (half,w) x 37 groups x 4 frags x 64 lanes (short8 entries)
#define GATE_E (16 * NGRP * 4 * 64) /* 151552 */
// z region: 8 waves x 32 groups x 2 frags x 64 lanes
#define Z_E (8 * 32 * 2 * 64)       /* 32768 */
#define NE_TOTAL (GATE_E + Z_E)     /* 184320 */
#define GATE_BYTES (GATE_E * 16)
#define Z_BYTES (Z_E * 16)
#define FLAGS_BYTES 16384
#define XSLOT_BYTES 16384

typedef short short8 __attribute__((ext_vector_type(8)));
typedef float floatx16 __attribute__((ext_vector_type(16)));

__device__ __forceinline__ unsigned short f2bf(float f) {
  unsigned int u = __float_as_uint(f);
  u += 0x7FFFu + ((u >> 16) & 1u);
  return (unsigned short)(u >> 16);
}
__device__ __forceinline__ float fsig(float x) {
  return __builtin_amdgcn_rcpf(1.0f + __builtin_amdgcn_exp2f(x * -1.4426950408889634f));
}
__device__ __forceinline__ float ftanh(float x) {
  return 1.0f - 2.0f * __builtin_amdgcn_rcpf(1.0f + __builtin_amdgcn_exp2f(x * 2.8853900817779268f));
}

// Pack weights (bf16). Gate region entry ((half*8+w)*37+gi)*4+f, lane:
//   gi<32: W_hh row n=f*512+half*256+w*32+l31, cols gi*16+hl*8..+7.
//   gi>=32: W_ih ext cols [noise 0..63][gap0][gap1][dp=0][clus][pad..79].
// Z region entry ((wz*32+gi)*2+s, lane): W1 row wz*64+s*32+l31, cols gi*16+hl*8.
// Also zeroes the pair-handshake flags (re-run every launch -> graph-safe).
__global__ void prep_pack(const float* __restrict__ Wih, const float* __restrict__ Whh,
                          const float* __restrict__ W1u, unsigned char* __restrict__ wsb) {
  const int idx = blockIdx.x * blockDim.x + threadIdx.x;
  if (idx < 4096) ((unsigned int*)(wsb + GATE_BYTES + Z_BYTES))[idx] = 0u;
  if (idx >= NE_TOTAL) return;
  unsigned short* us = (unsigned short*)wsb;
  const int lane = idx & 63;
  const int l31 = lane & 31, hl = lane >> 5;
  unsigned short v8[8];
  if (idx < GATE_E) {
    const int t1 = idx >> 6;
    const int f = t1 & 3;
    const int t2 = t1 >> 2;
    const int gi = t2 % NGRP;
    const int hw = t2 / NGRP;        // 0..15
    const int w = hw & 7, half = hw >> 3;
    const int n = f * Hn + half * 256 + w * 32 + l31;
    if (gi < 32) {
      const int k0 = gi * 16 + hl * 8;
#pragma unroll
      for (int j = 0; j < 8; ++j) v8[j] = f2bf(Whh[n * Hn + k0 + j]);
    } else {
      const int cb = (gi - 32) * 16 + hl * 8;
#pragma unroll
      for (int j = 0; j < 8; ++j) {
        const int c = cb + j;
        float v = 0.0f;
        if (c < 64) v = Wih[n * INn + 3 + c];
        else if (c == 64) v = Wih[n * INn + 0];
        else if (c == 65) v = Wih[n * INn + 1];
        else if (c == 67) v = Wih[n * INn + 67];
        v8[j] = f2bf(v);
      }
    }
  } else {
    const int e = idx - GATE_E;
    const int t1 = e >> 6;
    const int s = t1 & 1;
    const int t2 = t1 >> 1;
    const int gi = t2 & 31;
    const int wz = t2 >> 5;          // 0..7
    const int n = wz * 64 + s * 32 + l31;
    const int k0 = gi * 16 + hl * 8;
#pragma unroll
    for (int j = 0; j < 8; ++j) v8[j] = f2bf(W1u[n * Hn + k0 + j]);
  }
  unsigned short* dst = us + (size_t)idx * 8;
#pragma unroll
  for (int j = 0; j < 8; ++j) dst[j] = v8[j];
}

// Column-split pair kernel: 256 blocks; pair (b, b^128) shares 32 batch rows.
// Each block: gates for its 256 hidden cols (waves 0..7, 4 frags/grp) + full z
// (waves 8..15, 2 frags/grp; dp replicated, bitwise equal in both halves).
// Per step the pair exchanges swizzled h-halves (16KB) via parity-double-
// buffered global slots with release/acquire flags.
__launch_bounds__(NTHREADS, 1)
__global__ void lstm_seq(const float* __restrict__ noise, const float* __restrict__ cluster,
                         const float* __restrict__ gap, const float* __restrict__ Wih,
                         const float* __restrict__ bih, const float* __restrict__ bhh,
                         const float* __restrict__ b1p, const float* __restrict__ W2p,
                         const float* __restrict__ b2p,
                         unsigned char* __restrict__ wsb,
                         float* __restrict__ out) {
  __shared__ __align__(16) unsigned short hA[MB * Hn];      // 32 KB, swizzled
  __shared__ __align__(16) unsigned short extA[MB * 128];   // 8 KB, swizzled
  __shared__ float partial[8][MB];
  __shared__ float dp_lds[MB];
  __shared__ char occupancy_pad[40960];  // forces 1 block/CU (83KB total LDS)

  const int tid = threadIdx.x;
  const int w = tid >> 6;          // 0..15
  const int lane = tid & 63;
  const int l31 = lane & 31;
  const int hl = lane >> 5;
  const int pair = blockIdx.x & (NPAIR - 1);
  const int half_id = blockIdx.x >> 7;
  const int r0 = pair * MB;
  if (out == nullptr) occupancy_pad[0] = 1;  // keep pad alive (unprovable)

  // same koff for both pair halves -> aligned sweeps, shared z lines in L2
  const int koff = (((blockIdx.x >> 3) & 15) * NGRP) >> 4;
  const int koffz = koff & 31;

  short8 zero8 = {0, 0, 0, 0, 0, 0, 0, 0};
  for (int i = tid; i < MB * Hn / 8; i += NTHREADS) ((short8*)hA)[i] = zero8;
  for (int i = tid; i < MB * 128 / 8; i += NTHREADS) ((short8*)extA)[i] = zero8;

  // role-specific loop invariants
  float biasv[4], wih2[4];
  float b1v0 = 0.f, b1v1 = 0.f, w2v0 = 0.f, w2v1 = 0.f;
  if (w < 8) {
#pragma unroll
    for (int g = 0; g < 4; ++g) {
      const int n = g * Hn + half_id * 256 + w * 32 + l31;
      biasv[g] = bih[n] + bhh[n];
      wih2[g] = Wih[n * INn + 2];
    }
  } else {
    const int wz = w - 8;
    b1v0 = b1p[wz * 64 + l31];      b1v1 = b1p[wz * 64 + 32 + l31];
    w2v0 = W2p[wz * 64 + l31];      w2v1 = W2p[wz * 64 + 32 + l31];
  }
  const float b2v = b2p[0];
  const float clusf = cluster[r0 + (tid & 31)];

  // stream bases
  const short8* const gs = (const short8*)wsb + (size_t)((half_id * 8 + (w & 7)) * NGRP) * 4 * 64 + lane;
  const short8* const zs = (const short8*)(wsb + GATE_BYTES) + (size_t)((w & 7) * 32) * 2 * 64 + lane;

  // exchange buffers / flags
  unsigned int* const flag_own = (unsigned int*)(wsb + GATE_BYTES + Z_BYTES) + (pair * 2 + half_id) * 16;
  unsigned int* const flag_pt  = (unsigned int*)(wsb + GATE_BYTES + Z_BYTES) + (pair * 2 + (half_id ^ 1)) * 16;
  char* const xb = (char*)wsb + GATE_BYTES + Z_BYTES + FLAGS_BYTES;
  char* const xout = xb + (size_t)((pair * 2 + half_id) * 2) * XSLOT_BYTES;
  char* const xin  = xb + (size_t)((pair * 2 + (half_id ^ 1)) * 2) * XSLOT_BYTES;

  // stage extras for t = 0 (waves 0..7)
  if (tid < 512) {
    const int row = tid >> 4, kq = (tid & 15) << 2;
    const float4 v = *(const float4*)(noise + ((size_t)(r0 + row) * Tn + 0) * NZ + kq);
    ushort4 hb;
    hb.x = f2bf(v.x); hb.y = f2bf(v.y); hb.z = f2bf(v.z); hb.w = f2bf(v.w);
    *(ushort4*)((char*)extA + row * 256 + ((kq << 1) ^ ((row & 15) << 4))) = hb;
    if (tid < MB) {
      const size_t gb = ((size_t)(r0 + tid) * (Tn + 1) + 0) * 2;
      ushort4 hg;
      hg.x = f2bf(gap[gb]); hg.y = f2bf(gap[gb + 1]); hg.z = 0; hg.w = f2bf(clusf);
      *(ushort4*)((char*)extA + tid * 256 + (128 ^ ((tid & 15) << 4))) = hg;
    }
  }

  float c_reg[16];
#pragma unroll
  for (int q = 0; q < 16; ++q) c_reg[q] = 0.f;

  __syncthreads();

  for (int t = 0; t <= Tn; ++t) {
    floatx16 acc[4];
    floatx16 zacc[2];

    if (w < 8) {
      // ---------------- gate sweep: 37 groups x 4 frags ----------------
#pragma unroll
      for (int g = 0; g < 4; ++g)
#pragma unroll
        for (int q = 0; q < 16; ++q) acc[g][q] = 0.f;

      auto wgrp = [&](int g) -> int {
        int x = g + koff;
        return (x >= NGRP) ? (x - NGRP) : x;
      };
      auto ldG = [&](int g, short8(&b)[4]) {
        const short8* p = gs + wgrp(g) * (4 * 64);
#pragma unroll
        for (int f = 0; f < 4; ++f) b[f] = p[f * 64];
      };
      auto consG = [&](int g, const short8(&b)[4]) {
        const int gw = wgrp(g);
        const int isH = (gw < 32) ? 1 : 0;
        const int gg = isH ? gw : (gw - 32);
        const int k0 = (gg << 4) + (hl << 3);
        const int rsh = isH ? 10 : 8;
        const int msk = isH ? l31 : (l31 & 15);
        const char* base = isH ? (const char*)hA : (const char*)extA;
        const short8 a = *(const short8*)(base + (l31 << rsh) + ((k0 << 1) ^ (msk << 4)));
        acc[0] = __builtin_amdgcn_mfma_f32_32x32x16_bf16(a, b[0], acc[0], 0, 0, 0);
        acc[1] = __builtin_amdgcn_mfma_f32_32x32x16_bf16(a, b[1], acc[1], 0, 0, 0);
        acc[2] = __builtin_amdgcn_mfma_f32_32x32x16_bf16(a, b[2], acc[2], 0, 0, 0);
        acc[3] = __builtin_amdgcn_mfma_f32_32x32x16_bf16(a, b[3], acc[3], 0, 0, 0);
      };

      short8 bufA[4], bufB[4];
      ldG(0, bufA);
      for (int ii = 0; ii < 18; ++ii) {
        const int g0 = 2 * ii;
        ldG(g0 + 1, bufB);
        consG(g0, bufA);
        ldG(g0 + 2, bufA);
        consG(g0 + 1, bufB);
      }
      consG(36, bufA);
    } else {
      // ---------------- z sweep: 32 groups x 2 frags ----------------
#pragma unroll
      for (int q = 0; q < 16; ++q) { zacc[0][q] = 0.f; zacc[1][q] = 0.f; }

      auto ldZ = [&](int g, short8(&b)[2]) {
        const int kz = (g + koffz) & 31;
        const short8* p = zs + kz * (2 * 64);
        b[0] = p[0];
        b[1] = p[64];
      };
      auto consZ = [&](int g, const short8(&b)[2]) {
        const int kz = (g + koffz) & 31;
        const int k0 = (kz << 4) + (hl << 3);
        const short8 a = *(const short8*)((const char*)hA + (l31 << 10) + ((k0 << 1) ^ (l31 << 4)));
        zacc[0] = __builtin_amdgcn_mfma_f32_32x32x16_bf16(a, b[0], zacc[0], 0, 0, 0);
        zacc[1] = __builtin_amdgcn_mfma_f32_32x32x16_bf16(a, b[1], zacc[1], 0, 0, 0);
      };

      short8 bufA[2], bufB[2];
      ldZ(0, bufA);
      for (int ii = 0; ii < 15; ++ii) {
        const int g0 = 2 * ii;
        ldZ(g0 + 1, bufB);
        consZ(g0, bufA);
        ldZ(g0 + 2, bufA);
        consZ(g0 + 1, bufB);
      }
      ldZ(31, bufB);
      consZ(30, bufA);
      consZ(31, bufB);

      // z finish + dp partials (identical arithmetic to R5)
      float part[16];
#pragma unroll
      for (int q = 0; q < 16; ++q) {
        const float z0 = ftanh(zacc[0][q] + b1v0);
        const float z1 = ftanh(zacc[1][q] + b1v1);
        part[q] = z0 * w2v0 + z1 * w2v1;
      }
#pragma unroll
      for (int m = 1; m <= 16; m <<= 1)
#pragma unroll
        for (int q = 0; q < 16; ++q) part[q] += __shfl_xor(part[q], m, 64);
      if (l31 == 0) {
#pragma unroll
        for (int q = 0; q < 16; ++q)
          partial[w - 8][(q & 3) + ((q >> 2) << 3) + (hl << 2)] = part[q];
      }
    }

    __syncthreads();  // B1

    if (tid < MB) {
      float ssum = b2v;
#pragma unroll
      for (int ww = 0; ww < 8; ++ww) ssum += partial[ww][tid];
      const float dpv = DPRv * ftanh(ssum);
      dp_lds[tid] = dpv;
      if (half_id == 0) {
        const size_t gb = ((size_t)(r0 + tid) * (Tn + 1) + t) * 2;
        const float g0 = gap[gb], g1 = gap[gb + 1];
        float* op = out + ((size_t)(r0 + tid) * (Tn + 1) + t) * 3;
        op[0] = g0; op[1] = g1; op[2] = dpv;
      }
    }
    if (t < Tn - 1 && tid < 512) {
      const int row = tid >> 4, kq = (tid & 15) << 2;
      const float4 v = *(const float4*)(noise + ((size_t)(r0 + row) * Tn + (t + 1)) * NZ + kq);
      ushort4 hb;
      hb.x = f2bf(v.x); hb.y = f2bf(v.y); hb.z = f2bf(v.z); hb.w = f2bf(v.w);
      *(ushort4*)((char*)extA + row * 256 + ((kq << 1) ^ ((row & 15) << 4))) = hb;
      if (tid < MB) {
        const size_t gb = ((size_t)(r0 + tid) * (Tn + 1) + (t + 1)) * 2;
        ushort4 hg;
        hg.x = f2bf(gap[gb]); hg.y = f2bf(gap[gb + 1]); hg.z = 0; hg.w = f2bf(clusf);
        *(ushort4*)((char*)extA + tid * 256 + (128 ^ ((tid & 15) << 4))) = hg;
      }
    }
    __syncthreads();  // B2

    if (t < Tn) {
      if (w < 8) {
        // cell update for own 256 cols; write swizzled h into own half
        float dpv[16];
#pragma unroll
        for (int q = 0; q < 16; ++q)
          dpv[q] = dp_lds[(q & 3) + ((q >> 2) << 3) + (hl << 2)];
        const int colb = (half_id * 256 + w * 32 + l31) << 1;
#pragma unroll
        for (int q = 0; q < 16; ++q) {
          const float gi = acc[0][q] + biasv[0] + dpv[q] * wih2[0];
          const float gf = acc[1][q] + biasv[1] + dpv[q] * wih2[1];
          const float gg = acc[2][q] + biasv[2] + dpv[q] * wih2[2];
          const float go = acc[3][q] + biasv[3] + dpv[q] * wih2[3];
          float cv = c_reg[q];
          cv = fsig(gf) * cv + fsig(gi) * ftanh(gg);
          const float hv = fsig(go) * ftanh(cv);
          c_reg[q] = cv;
          const int r = (q & 3) + ((q >> 2) << 3) + (hl << 2);
          *(unsigned short*)((char*)hA + (r << 10) + (colb ^ (r << 4))) = f2bf(hv);
        }
      }
      __syncthreads();  // B3: own half complete in LDS

      // copy-out own swizzled half (raw bytes): 1024 thr x 16B = 16KB
      const int parity = (t + 1) & 1;
      {
        const int row = tid >> 5, off = (tid & 31) << 4;
        const short8 v = *(const short8*)((char*)hA + (row << 10) + (half_id << 9) + off);
        *(short8*)(xout + (size_t)parity * XSLOT_BYTES + (row << 9) + off) = v;
      }
      __threadfence();
      __syncthreads();  // B4: all copy-out stores agent-visible

      if (tid == 0) {
        __hip_atomic_store(flag_own, (unsigned int)(t + 1), __ATOMIC_RELEASE, __HIP_MEMORY_SCOPE_AGENT);
        while (__hip_atomic_load(flag_pt, __ATOMIC_ACQUIRE, __HIP_MEMORY_SCOPE_AGENT) < (unsigned int)(t + 1))
          __builtin_amdgcn_s_sleep(2);
      }
      __syncthreads();  // B5: partner data ready

      // per-thread acquire (L1 coherence for the copy-in loads)
      unsigned int fv = __hip_atomic_load(flag_pt, __ATOMIC_ACQUIRE, __HIP_MEMORY_SCOPE_AGENT);
      asm volatile("" ::"v"(fv));

      // copy-in partner half into LDS
      {
        const int row = tid >> 5, off = (tid & 31) << 4;
        const short8 v = *(const short8*)(xin + (size_t)parity * XSLOT_BYTES + (row << 9) + off);
        *(short8*)((char*)hA + (row << 10) + ((half_id ^ 1) << 9) + off) = v;
      }
      __syncthreads();  // B6: hA ready for next step
    }
  }
}

extern "C" void kernel_launch(void* const* d_in, const int* in_sizes, int n_in,
                              void* d_out, int out_size, void* d_ws, size_t ws_size,
                              hipStream_t stream) {
  const float* noise   = (const float*)d_in[0];
  const float* cluster = (const float*)d_in[1];
  const float* gap     = (const float*)d_in[2];
  const float* Wih     = (const float*)d_in[3];
  const float* Whh     = (const float*)d_in[4];
  const float* bih     = (const float*)d_in[5];
  const float* bhh     = (const float*)d_in[6];
  const float* W1      = (const float*)d_in[7];
  const float* b1      = (const float*)d_in[8];
  const float* W2      = (const float*)d_in[9];
  const float* b2      = (const float*)d_in[10];

  unsigned char* wsb = (unsigned char*)d_ws;  // streams 2.95MB + flags 16KB + xbuf 8MB

  prep_pack<<<(NE_TOTAL + 255) / 256, 256, 0, stream>>>(Wih, Whh, W1, wsb);
  lstm_seq<<<NBLK, NTHREADS, 0, stream>>>(noise, cluster, gap, Wih, bih, bhh, b1, W2, b2,
                                          wsb, (float*)d_out);
}

// Round 13
// 23898.445 us; speedup vs baseline: 1.7231x; 1.7231x over previous
//
#include <hip/hip_runtime.h>

#define Bn 4096
#define Tn 256
#define NZ 64
#define Hn 512
#define INn 68
#define DPRv 24.0f
#define MB 32
#define NWAVE 8
#define NTHREADS 512
#define NBLK 128

// unified per-wave weight stream: 37 groups (32 h + 5 ext) x 10 frags x 64 lanes x 16B
#define NGRP 37
#define GRP_BYTES 10240
#define WAVE_BYTES (NGRP * GRP_BYTES)       /* 378880 */
#define STREAM_SHORTS (NWAVE * NGRP * 10 * 64 * 8) /* 1515520 */
#define NSLOT 13                            /* ring slots per wave, 12 DMAs in flight */

typedef short short8 __attribute__((ext_vector_type(8)));
typedef float floatx16 __attribute__((ext_vector_type(16)));

__device__ __forceinline__ unsigned short f2bf(float f) {
  unsigned int u = __float_as_uint(f);
  u += 0x7FFFu + ((u >> 16) & 1u);
  return (unsigned short)(u >> 16);
}
__device__ __forceinline__ float fsig(float x) {
  return __builtin_amdgcn_rcpf(1.0f + __builtin_amdgcn_exp2f(x * -1.4426950408889634f));
}
__device__ __forceinline__ float ftanh(float x) {
  return 1.0f - 2.0f * __builtin_amdgcn_rcpf(1.0f + __builtin_amdgcn_exp2f(x * 2.8853900817779268f));
}
// async global->LDS DMA, 16B/lane: lds dest = uniform base + lane*16 (HW), global src per-lane
__device__ __forceinline__ void dma16(const void* gp, void* lp) {
  __builtin_amdgcn_global_load_lds(
      (const __attribute__((address_space(1))) void*)gp,
      (__attribute__((address_space(3))) void*)lp, 16, 0, 0);
}

// Pack all weights (bf16) into the unified per-(wave,group,frag,lane) stream (R9-identical).
// Group gi<32: K-slice gi of h. frags 0,1 -> W1 (z); frags 2..9 -> W_hh (gate g, sub s).
// Group gi>=32: ext K-slice. frags 0,1 -> ZERO; frags 2..9 -> W_ih rearranged cols
//   [noise 0..63][gap0][gap1][dp=0][clus][pad..79].
__global__ void prep_pack(const float* __restrict__ Wih, const float* __restrict__ Whh,
                          const float* __restrict__ W1u, unsigned short* __restrict__ us) {
  const int idx = blockIdx.x * blockDim.x + threadIdx.x;
  if (idx >= STREAM_SHORTS / 8) return;
  const int lane = idx & 63;
  const int fragid = idx >> 6;
  const int f = fragid % 10;
  const int gi = (fragid / 10) % NGRP;
  const int w = fragid / (10 * NGRP);
  const int l31 = lane & 31, half = lane >> 5;
  unsigned short v8[8];
  if (gi < 32) {
    const int k0 = gi * 16 + half * 8;
    if (f < 2) {
      const int n = w * 64 + f * 32 + l31;
#pragma unroll
      for (int j = 0; j < 8; ++j) v8[j] = f2bf(W1u[n * Hn + k0 + j]);
    } else {
      const int g = (f - 2) >> 1, s = (f - 2) & 1;
      const int n = g * Hn + w * 64 + s * 32 + l31;
#pragma unroll
      for (int j = 0; j < 8; ++j) v8[j] = f2bf(Whh[n * Hn + k0 + j]);
    }
  } else {
    const int kk = gi - 32;
    const int cb = kk * 16 + half * 8;
    if (f < 2) {
#pragma unroll
      for (int j = 0; j < 8; ++j) v8[j] = 0;
    } else {
      const int g = (f - 2) >> 1, s = (f - 2) & 1;
      const int n = g * Hn + w * 64 + s * 32 + l31;
#pragma unroll
      for (int j = 0; j < 8; ++j) {
        const int c = cb + j;
        float v = 0.0f;
        if (c < 64) v = Wih[n * INn + 3 + c];
        else if (c == 64) v = Wih[n * INn + 0];
        else if (c == 65) v = Wih[n * INn + 1];
        else if (c == 67) v = Wih[n * INn + 67];
        v8[j] = f2bf(v);
      }
    }
  }
  unsigned short* dst = us + (size_t)idx * 8;
#pragma unroll
  for (int j = 0; j < 8; ++j) dst[j] = v8[j];
}

// Persistent recurrent kernel, R9 math, weight stream via global_load_lds ring:
// 13-slot x 1KB LDS ring per wave, 12 DMAs steadily in flight, counted vmcnt(11)
// before each consume. No compiler vmem inside the sweep (epilogue I/O after a
// vmcnt(0) drain; __syncthreads drains counters between phases).
__launch_bounds__(NTHREADS, 2)
__global__ void lstm_seq(const float* __restrict__ noise, const float* __restrict__ cluster,
                         const float* __restrict__ gap, const float* __restrict__ Wih,
                         const float* __restrict__ bih, const float* __restrict__ bhh,
                         const float* __restrict__ b1p, const float* __restrict__ W2p,
                         const float* __restrict__ b2p,
                         const unsigned short* __restrict__ us,
                         float* __restrict__ out) {
  __shared__ __align__(16) unsigned short hA[MB * Hn];      // 32 KB, swizzled A-layout
  __shared__ __align__(16) unsigned short extA[MB * 128];   // 8 KB, swizzled
  __shared__ float partial[NWAVE][MB];
  __shared__ float dp_lds[MB];
  __shared__ __align__(1024) char ring[NWAVE][NSLOT * 1024]; // 104 KB DMA ring

  const int tid = threadIdx.x;
  const int w = tid >> 6;
  const int lane = tid & 63;
  const int l31 = lane & 31;
  const int hl = lane >> 5;
  const int r0 = blockIdx.x * MB;
  const int cb = w * 64;
  const int c0 = cb + l31;
  const int c1 = cb + 32 + l31;
  const int lane16 = lane * 16;

  const int koff = (((blockIdx.x >> 3) & 15) * NGRP) >> 4;  // phase rotation (R9)

  short8 zero8 = {0, 0, 0, 0, 0, 0, 0, 0};
  for (int i = tid; i < MB * Hn / 8; i += NTHREADS) ((short8*)hA)[i] = zero8;
  for (int i = tid; i < MB * 128 / 8; i += NTHREADS) ((short8*)extA)[i] = zero8;

  float biasv[4][2], wih2[4][2];
#pragma unroll
  for (int g = 0; g < 4; ++g)
#pragma unroll
    for (int s = 0; s < 2; ++s) {
      int n = g * Hn + cb + s * 32 + l31;
      biasv[g][s] = bih[n] + bhh[n];
      wih2[g][s] = Wih[n * INn + 2];
    }
  const float b1v0 = b1p[c0], b1v1 = b1p[c1];
  const float w2v0 = W2p[c0], w2v1 = W2p[c1];
  const float b2v = b2p[0];
  const float clusf = cluster[r0 + (tid & 31)];

  const char* const wsB = (const char*)us + (size_t)w * WAVE_BYTES;
  char* const myring = &ring[w][0];

  // stage extras for t = 0
  {
    const int row = tid >> 4, kq = (tid & 15) << 2;
    const float4 v = *(const float4*)(noise + ((size_t)(r0 + row) * Tn + 0) * NZ + kq);
    ushort4 hb;
    hb.x = f2bf(v.x); hb.y = f2bf(v.y); hb.z = f2bf(v.z); hb.w = f2bf(v.w);
    *(ushort4*)((char*)extA + row * 256 + ((kq << 1) ^ ((row & 15) << 4))) = hb;
    if (tid < MB) {
      const size_t gb = ((size_t)(r0 + tid) * (Tn + 1) + 0) * 2;
      ushort4 hg;
      hg.x = f2bf(gap[gb]); hg.y = f2bf(gap[gb + 1]); hg.z = 0; hg.w = f2bf(clusf);
      *(ushort4*)((char*)extA + tid * 256 + (128 ^ ((tid & 15) << 4))) = hg;
    }
  }

  float c_reg0[16], c_reg1[16];
#pragma unroll
  for (int q = 0; q < 16; ++q) { c_reg0[q] = 0.f; c_reg1[q] = 0.f; }

  __syncthreads();

  for (int t = 0; t <= Tn; ++t) {
    floatx16 zacc[2];
    floatx16 acc[4][2];
#pragma unroll
    for (int s = 0; s < 2; ++s)
#pragma unroll
      for (int q = 0; q < 16; ++q) zacc[s][q] = 0.f;
#pragma unroll
    for (int g = 0; g < 4; ++g)
#pragma unroll
      for (int s = 0; s < 2; ++s)
#pragma unroll
        for (int q = 0; q < 16; ++q) acc[g][s][q] = 0.f;

    auto wgrp = [&](int g) -> int {
      int x = g + koff;
      return (x >= NGRP) ? (x - NGRP) : x;
    };
    auto afrag = [&](int gw) -> short8 {
      const int isH = (gw < 32) ? 1 : 0;
      const int gg = isH ? gw : (gw - 32);
      const int k0 = (gg << 4) + (hl << 3);
      const int rsh = isH ? 10 : 8;
      const int msk = isH ? l31 : (l31 & 15);
      const char* base = isH ? (const char*)hA : (const char*)extA;
      return *(const short8*)(base + (l31 << rsh) + ((k0 << 1) ^ (msk << 4)));
    };
    auto domf = [&](int f, short8 a, short8 b) {
      if (f == 0)      zacc[0] = __builtin_amdgcn_mfma_f32_32x32x16_bf16(a, b, zacc[0], 0, 0, 0);
      else if (f == 1) zacc[1] = __builtin_amdgcn_mfma_f32_32x32x16_bf16(a, b, zacc[1], 0, 0, 0);
      else {
        const int g2 = (f - 2) >> 1, s = (f - 2) & 1;
        acc[g2][s] = __builtin_amdgcn_mfma_f32_32x32x16_bf16(a, b, acc[g2][s], 0, 0, 0);
      }
    };

    // ---- prologue: issue frags 0..11 (vmcnt is clean after the last barrier) ----
    {
      const char* b0 = wsB + (size_t)wgrp(0) * GRP_BYTES;
      const char* b1 = wsB + (size_t)wgrp(1) * GRP_BYTES;
#pragma unroll
      for (int f = 0; f < 10; ++f) dma16(b0 + f * 1024 + lane16, myring + f * 1024);
      dma16(b1 + lane16, myring + 10 * 1024);
      dma16(b1 + 1024 + lane16, myring + 11 * 1024);
    }
    int slot = 0, islot = 12;

    // ---- main sweep: groups 0..34 (flat frags 0..349), steady 12 in flight ----
    for (int g = 0; g < 35; ++g) {
      const short8 a = afrag(wgrp(g));
      const char* ib1 = wsB + (size_t)wgrp(g + 1) * GRP_BYTES;
      const char* ib2 = wsB + (size_t)wgrp(g + 2) * GRP_BYTES;
#pragma unroll
      for (int f = 0; f < 10; ++f) {
        asm volatile("s_waitcnt vmcnt(11)" ::: "memory");
        const short8 b = *(const short8*)(myring + slot * 1024 + lane16);
        // issue frag FI+12: f<8 -> (g+1, f+2); f>=8 -> (g+2, f-8). Target slot
        // (islot) held frag FI-1, consumed last iteration -> no overwrite race.
        dma16((f < 8 ? ib1 + (f + 2) * 1024 : ib2 + (f - 8) * 1024) + lane16,
              myring + islot * 1024);
        domf(f, a, b);
        slot = (slot == NSLOT - 1) ? 0 : slot + 1;
        islot = (islot == NSLOT - 1) ? 0 : islot + 1;
      }
    }
    // ---- tail: group 35 (issue the last 8), drain, consume 358..369 ----
    {
      const int gw35 = wgrp(35), gw36 = wgrp(36);
      const short8 a35 = afrag(gw35);
      const char* ib = wsB + (size_t)gw36 * GRP_BYTES;
#pragma unroll
      for (int f = 0; f < 8; ++f) {
        asm volatile("s_waitcnt vmcnt(11)" ::: "memory");
        const short8 b = *(const short8*)(myring + slot * 1024 + lane16);
        dma16(ib + (f + 2) * 1024 + lane16, myring + islot * 1024);
        domf(f, a35, b);
        slot = (slot == NSLOT - 1) ? 0 : slot + 1;
        islot = (islot == NSLOT - 1) ? 0 : islot + 1;
      }
      asm volatile("s_waitcnt vmcnt(0)" ::: "memory");
      const short8 b8 = *(const short8*)(myring + slot * 1024 + lane16);
      slot = (slot == NSLOT - 1) ? 0 : slot + 1;
      const short8 b9 = *(const short8*)(myring + slot * 1024 + lane16);
      slot = (slot == NSLOT - 1) ? 0 : slot + 1;
      domf(8, a35, b8);
      domf(9, a35, b9);
      const short8 a36 = afrag(gw36);
#pragma unroll
      for (int f = 0; f < 10; ++f) {
        const short8 b = *(const short8*)(myring + slot * 1024 + lane16);
        domf(f, a36, b);
        slot = (slot == NSLOT - 1) ? 0 : slot + 1;
      }
    }

    // z finish + dp partials
    {
      float part[16];
#pragma unroll
      for (int q = 0; q < 16; ++q) {
        const float z0 = ftanh(zacc[0][q] + b1v0);
        const float z1 = ftanh(zacc[1][q] + b1v1);
        part[q] = z0 * w2v0 + z1 * w2v1;
      }
#pragma unroll
      for (int m = 1; m <= 16; m <<= 1)
#pragma unroll
        for (int q = 0; q < 16; ++q) part[q] += __shfl_xor(part[q], m, 64);
      if (l31 == 0) {
#pragma unroll
        for (int q = 0; q < 16; ++q)
          partial[w][(q & 3) + ((q >> 2) << 3) + (hl << 2)] = part[q];
      }
    }

    __syncthreads();  // B1: partial complete; all reads of hA/extA/ring complete

    if (tid < MB) {
      float ssum = b2v;
#pragma unroll
      for (int ww = 0; ww < NWAVE; ++ww) ssum += partial[ww][tid];
      const float dpv = DPRv * ftanh(ssum);
      dp_lds[tid] = dpv;
      const size_t gb = ((size_t)(r0 + tid) * (Tn + 1) + t) * 2;
      const float g0 = gap[gb], g1 = gap[gb + 1];
      float* op = out + ((size_t)(r0 + tid) * (Tn + 1) + t) * 3;
      op[0] = g0; op[1] = g1; op[2] = dpv;
    }
    if (t < Tn - 1) {
      const int row = tid >> 4, kq = (tid & 15) << 2;
      const float4 v = *(const float4*)(noise + ((size_t)(r0 + row) * Tn + (t + 1)) * NZ + kq);
      ushort4 hb;
      hb.x = f2bf(v.x); hb.y = f2bf(v.y); hb.z = f2bf(v.z); hb.w = f2bf(v.w);
      *(ushort4*)((char*)extA + row * 256 + ((kq << 1) ^ ((row & 15) << 4))) = hb;
      if (tid < MB) {
        const size_t gb = ((size_t)(r0 + tid) * (Tn + 1) + (t + 1)) * 2;
        ushort4 hg;
        hg.x = f2bf(gap[gb]); hg.y = f2bf(gap[gb + 1]); hg.z = 0; hg.w = f2bf(clusf);
        *(ushort4*)((char*)extA + tid * 256 + (128 ^ ((tid & 15) << 4))) = hg;
      }
    }
    __syncthreads();  // B2: dp_lds visible; hA safe to overwrite

    if (t < Tn) {
      float dpv[16];
#pragma unroll
      for (int q = 0; q < 16; ++q)
        dpv[q] = dp_lds[(q & 3) + ((q >> 2) << 3) + (hl << 2)];
#pragma unroll
      for (int s = 0; s < 2; ++s) {
        const int colb = (cb + s * 32 + l31) << 1;
#pragma unroll
        for (int q = 0; q < 16; ++q) {
          const float gi = acc[0][s][q] + biasv[0][s] + dpv[q] * wih2[0][s];
          const float gf = acc[1][s][q] + biasv[1][s] + dpv[q] * wih2[1][s];
          const float gg = acc[2][s][q] + biasv[2][s] + dpv[q] * wih2[2][s];
          const float go = acc[3][s][q] + biasv[3][s] + dpv[q] * wih2[3][s];
          float cv = (s == 0) ? c_reg0[q] : c_reg1[q];
          cv = fsig(gf) * cv + fsig(gi) * ftanh(gg);
          const float hv = fsig(go) * ftanh(cv);
          if (s == 0) c_reg0[q] = cv; else c_reg1[q] = cv;
          const int r = (q & 3) + ((q >> 2) << 3) + (hl << 2);
          *(unsigned short*)((char*)hA + (r << 10) + (colb ^ (r << 4))) = f2bf(hv);
        }
      }
    }
    __syncthreads();  // B3: hA ready for next step; vmcnt drained at barrier
  }
}

extern "C" void kernel_launch(void* const* d_in, const int* in_sizes, int n_in,
                              void* d_out, int out_size, void* d_ws, size_t ws_size,
                              hipStream_t stream) {
  const float* noise   = (const float*)d_in[0];
  const float* cluster = (const float*)d_in[1];
  const float* gap     = (const float*)d_in[2];
  const float* Wih     = (const float*)d_in[3];
  const float* Whh     = (const float*)d_in[4];
  const float* bih     = (const float*)d_in[5];
  const float* bhh     = (const float*)d_in[6];
  const float* W1      = (const float*)d_in[7];
  const float* b1      = (const float*)d_in[8];
  const float* W2      = (const float*)d_in[9];
  const float* b2      = (const float*)d_in[10];

  unsigned short* us = (unsigned short*)d_ws;  // 3.03 MB packed stream

  prep_pack<<<(STREAM_SHORTS / 8 + 255) / 256, 256, 0, stream>>>(Wih, Whh, W1, us);
  lstm_seq<<<NBLK, NTHREADS, 0, stream>>>(noise, cluster, gap, Wih, bih, bhh, b1, W2, b2,
                                          us, (float*)d_out);
}

// Round 14
// 11992.586 us; speedup vs baseline: 3.4338x; 1.9928x over previous
//
#include <hip/hip_runtime.h>

#define Bn 4096
#define Tn 256
#define NZ 64
#define Hn 512
#define INn 68
#define DPRv 24.0f
#define MB 32
#define NWAVE 8
#define NTHREADS 512
#define NBLK 128

// unified per-wave weight stream: 37 groups (32 h + 5 ext) x 10 frags x 64 lanes x 8 shorts
#define NGRP 37
#define GRP_SHORTS (10 * 64 * 8)            /* 5120 */
#define WAVE_SHORTS (NGRP * GRP_SHORTS)     /* 189440 */
#define STREAM_SHORTS (NWAVE * WAVE_SHORTS) /* 1515520 */

typedef short short8 __attribute__((ext_vector_type(8)));
typedef float floatx16 __attribute__((ext_vector_type(16)));
typedef float f4 __attribute__((ext_vector_type(4)));

__device__ __forceinline__ unsigned short f2bf(float f) {
  unsigned int u = __float_as_uint(f);
  u += 0x7FFFu + ((u >> 16) & 1u);
  return (unsigned short)(u >> 16);
}
__device__ __forceinline__ float fsig(float x) {
  return __builtin_amdgcn_rcpf(1.0f + __builtin_amdgcn_exp2f(x * -1.4426950408889634f));
}
__device__ __forceinline__ float ftanh(float x) {
  return 1.0f - 2.0f * __builtin_amdgcn_rcpf(1.0f + __builtin_amdgcn_exp2f(x * 2.8853900817779268f));
}

// Pack all weights (bf16) into the unified per-(wave,group,frag,lane) stream (R9-identical).
__global__ void prep_pack(const float* __restrict__ Wih, const float* __restrict__ Whh,
                          const float* __restrict__ W1u, unsigned short* __restrict__ us) {
  const int idx = blockIdx.x * blockDim.x + threadIdx.x;
  if (idx >= STREAM_SHORTS / 8) return;
  const int lane = idx & 63;
  const int fragid = idx >> 6;
  const int f = fragid % 10;
  const int gi = (fragid / 10) % NGRP;
  const int w = fragid / (10 * NGRP);
  const int l31 = lane & 31, half = lane >> 5;
  unsigned short v8[8];
  if (gi < 32) {
    const int k0 = gi * 16 + half * 8;
    if (f < 2) {
      const int n = w * 64 + f * 32 + l31;
#pragma unroll
      for (int j = 0; j < 8; ++j) v8[j] = f2bf(W1u[n * Hn + k0 + j]);
    } else {
      const int g = (f - 2) >> 1, s = (f - 2) & 1;
      const int n = g * Hn + w * 64 + s * 32 + l31;
#pragma unroll
      for (int j = 0; j < 8; ++j) v8[j] = f2bf(Whh[n * Hn + k0 + j]);
    }
  } else {
    const int kk = gi - 32;
    const int cb = kk * 16 + half * 8;
    if (f < 2) {
#pragma unroll
      for (int j = 0; j < 8; ++j) v8[j] = 0;
    } else {
      const int g = (f - 2) >> 1, s = (f - 2) & 1;
      const int n = g * Hn + w * 64 + s * 32 + l31;
#pragma unroll
      for (int j = 0; j < 8; ++j) {
        const int c = cb + j;
        float v = 0.0f;
        if (c < 64) v = Wih[n * INn + 3 + c];
        else if (c == 64) v = Wih[n * INn + 0];
        else if (c == 65) v = Wih[n * INn + 1];
        else if (c == 67) v = Wih[n * INn + 67];
        v8[j] = f2bf(v);
      }
    }
  }
  unsigned short* dst = us + (size_t)idx * 8;
#pragma unroll
  for (int j = 0; j < 8; ++j) dst[j] = v8[j];
}

// R9 sweep + single-barrier step: hA/extA parity double-buffered, dp via LDS
// flags (no B1/B2 barriers), each wave computes dp for its own rows.
__launch_bounds__(NTHREADS, 2)
__global__ void lstm_seq(const float* __restrict__ noise, const float* __restrict__ cluster,
                         const float* __restrict__ gap, const float* __restrict__ Wih,
                         const float* __restrict__ bih, const float* __restrict__ bhh,
                         const float* __restrict__ b1p, const float* __restrict__ W2p,
                         const float* __restrict__ b2p,
                         const unsigned short* __restrict__ us,
                         float* __restrict__ out) {
  __shared__ __align__(16) unsigned short hA[2][MB * Hn];    // 64 KB, swizzled, parity
  __shared__ __align__(16) unsigned short extA[2][MB * 128]; // 16 KB, swizzled, parity
  __shared__ float partial[MB][NWAVE];                       // [row][wave]
  __shared__ int flags[NWAVE];

  const int tid = threadIdx.x;
  const int w = tid >> 6;
  const int lane = tid & 63;
  const int l31 = lane & 31;
  const int hl = lane >> 5;
  const int r0 = blockIdx.x * MB;
  const int cb = w * 64;
  const int c0 = cb + l31;
  const int c1 = cb + 32 + l31;

  const int koff = (((blockIdx.x >> 3) & 15) * NGRP) >> 4;  // phase rotation (R9)

  short8 zero8 = {0, 0, 0, 0, 0, 0, 0, 0};
  for (int i = tid; i < MB * Hn / 8; i += NTHREADS) ((short8*)&hA[0][0])[i] = zero8;
  for (int i = tid; i < 2 * MB * 128 / 8; i += NTHREADS) ((short8*)&extA[0][0])[i] = zero8;
  if (tid < NWAVE) flags[tid] = 0;

  float biasv[4][2], wih2[4][2];
#pragma unroll
  for (int g = 0; g < 4; ++g)
#pragma unroll
    for (int s = 0; s < 2; ++s) {
      int n = g * Hn + cb + s * 32 + l31;
      biasv[g][s] = bih[n] + bhh[n];
      wih2[g][s] = Wih[n * INn + 2];
    }
  const float b1v0 = b1p[c0], b1v1 = b1p[c1];
  const float w2v0 = W2p[c0], w2v1 = W2p[c1];
  const float b2v = b2p[0];
  const float clusf = cluster[r0 + (tid & 31)];

  const short8* const ws = (const short8*)us + (size_t)w * (NGRP * 10 * 64) + lane;

  // stage extras for t = 0 into parity 0
  {
    const int row = tid >> 4, kq = (tid & 15) << 2;
    const float4 v = *(const float4*)(noise + ((size_t)(r0 + row) * Tn + 0) * NZ + kq);
    ushort4 hb;
    hb.x = f2bf(v.x); hb.y = f2bf(v.y); hb.z = f2bf(v.z); hb.w = f2bf(v.w);
    *(ushort4*)((char*)&extA[0][0] + row * 256 + ((kq << 1) ^ ((row & 15) << 4))) = hb;
    if (tid < MB) {
      const size_t gb = ((size_t)(r0 + tid) * (Tn + 1) + 0) * 2;
      ushort4 hg;
      hg.x = f2bf(gap[gb]); hg.y = f2bf(gap[gb + 1]); hg.z = 0; hg.w = f2bf(clusf);
      *(ushort4*)((char*)&extA[0][0] + tid * 256 + (128 ^ ((tid & 15) << 4))) = hg;
    }
  }

  float c_reg0[16], c_reg1[16];
#pragma unroll
  for (int q = 0; q < 16; ++q) { c_reg0[q] = 0.f; c_reg1[q] = 0.f; }

  __syncthreads();

  int p = 0;
  for (int t = 0; t <= Tn; ++t) {
    const unsigned short* hAp = &hA[p][0];
    const unsigned short* extAp = &extA[p][0];
    unsigned short* hAq = &hA[p ^ 1][0];
    unsigned short* extAq = &extA[p ^ 1][0];

    floatx16 zacc[2];
    floatx16 acc[4][2];
#pragma unroll
    for (int s = 0; s < 2; ++s)
#pragma unroll
      for (int q = 0; q < 16; ++q) zacc[s][q] = 0.f;
#pragma unroll
    for (int g = 0; g < 4; ++g)
#pragma unroll
      for (int s = 0; s < 2; ++s)
#pragma unroll
        for (int q = 0; q < 16; ++q) acc[g][s][q] = 0.f;

    auto wgrp = [&](int g) -> int {
      int x = g + koff;
      return (x >= NGRP) ? (x - NGRP) : x;
    };
    auto ldgrp = [&](int g, short8(&b)[10]) {
      const short8* pp = ws + wgrp(g) * (10 * 64);
#pragma unroll
      for (int f = 0; f < 10; ++f) b[f] = pp[f * 64];
    };
    auto consume = [&](int g, const short8(&b)[10]) {
      const int gw = wgrp(g);
      const int isH = (gw < 32) ? 1 : 0;
      const int gg = isH ? gw : (gw - 32);
      const int k0 = (gg << 4) + (hl << 3);
      const int rsh = isH ? 10 : 8;
      const int msk = isH ? l31 : (l31 & 15);
      const char* base = isH ? (const char*)hAp : (const char*)extAp;
      const short8 a = *(const short8*)(base + (l31 << rsh) + ((k0 << 1) ^ (msk << 4)));
      zacc[0] = __builtin_amdgcn_mfma_f32_32x32x16_bf16(a, b[0], zacc[0], 0, 0, 0);
      zacc[1] = __builtin_amdgcn_mfma_f32_32x32x16_bf16(a, b[1], zacc[1], 0, 0, 0);
#pragma unroll
      for (int g2 = 0; g2 < 4; ++g2)
#pragma unroll
        for (int s = 0; s < 2; ++s)
          acc[g2][s] = __builtin_amdgcn_mfma_f32_32x32x16_bf16(a, b[2 + g2 * 2 + s], acc[g2][s], 0, 0, 0);
    };

    short8 bufA[10], bufB[10];
    ldgrp(0, bufA);
    for (int ii = 0; ii < 18; ++ii) {
      const int g0 = 2 * ii;
      ldgrp(g0 + 1, bufB);
      consume(g0, bufA);
      ldgrp(g0 + 2, bufA);
      consume(g0 + 1, bufB);
    }
    consume(36, bufA);

    // ---- z finish: post partials [row][w], fence, raise flag ----
    {
      float part[16];
#pragma unroll
      for (int q = 0; q < 16; ++q) {
        const float z0 = ftanh(zacc[0][q] + b1v0);
        const float z1 = ftanh(zacc[1][q] + b1v1);
        part[q] = z0 * w2v0 + z1 * w2v1;
      }
#pragma unroll
      for (int m = 1; m <= 16; m <<= 1)
#pragma unroll
        for (int q = 0; q < 16; ++q) part[q] += __shfl_xor(part[q], m, 64);
      if (l31 == 0) {
#pragma unroll
        for (int q = 0; q < 16; ++q)
          partial[(q & 3) + ((q >> 2) << 3) + (hl << 2)][w] = part[q];
      }
      asm volatile("s_waitcnt lgkmcnt(0)" ::: "memory");
      if (lane == 0)
        __hip_atomic_store(&flags[w], t + 1, __ATOMIC_RELAXED, __HIP_MEMORY_SCOPE_WORKGROUP);
    }

    // ---- stage extras for t+1 into parity^1 (overlaps other waves' tails) ----
    if (t < Tn - 1) {
      const int row = tid >> 4, kq = (tid & 15) << 2;
      const float4 v = *(const float4*)(noise + ((size_t)(r0 + row) * Tn + (t + 1)) * NZ + kq);
      ushort4 hb;
      hb.x = f2bf(v.x); hb.y = f2bf(v.y); hb.z = f2bf(v.z); hb.w = f2bf(v.w);
      *(ushort4*)((char*)extAq + row * 256 + ((kq << 1) ^ ((row & 15) << 4))) = hb;
      if (tid < MB) {
        const size_t gb = ((size_t)(r0 + tid) * (Tn + 1) + (t + 1)) * 2;
        ushort4 hg;
        hg.x = f2bf(gap[gb]); hg.y = f2bf(gap[gb + 1]); hg.z = 0; hg.w = f2bf(clusf);
        *(ushort4*)((char*)extAq + tid * 256 + (128 ^ ((tid & 15) << 4))) = hg;
      }
    }

    // ---- wait for all waves' z partials (LDS flags; no barrier, no vm drain) ----
#pragma unroll
    for (int w2 = 0; w2 < NWAVE; ++w2) {
      while (__hip_atomic_load(&flags[w2], __ATOMIC_RELAXED, __HIP_MEMORY_SCOPE_WORKGROUP) < t + 1)
        __builtin_amdgcn_s_sleep(1);
    }

    // ---- dp for this wave's rows (deterministic fixed-order sum) ----
    auto dp_row = [&](int row) -> float {
      const f4 p0 = *(const f4*)&partial[row][0];
      const f4 p1 = *(const f4*)&partial[row][4];
      const float s8 = ((p0.x + p0.y) + (p0.z + p0.w)) + ((p1.x + p1.y) + (p1.z + p1.w));
      return DPRv * ftanh(b2v + s8);
    };

    // wave 0 lanes 0..31: output row = lane
    if (tid < MB) {
      const float dpv = dp_row(tid);
      const size_t gb = ((size_t)(r0 + tid) * (Tn + 1) + t) * 2;
      const float g0 = gap[gb], g1 = gap[gb + 1];
      float* op = out + ((size_t)(r0 + tid) * (Tn + 1) + t) * 3;
      op[0] = g0; op[1] = g1; op[2] = dpv;
    }

    // ---- cell update into parity^1 ----
    if (t < Tn) {
      float dpv[16];
#pragma unroll
      for (int q = 0; q < 16; ++q)
        dpv[q] = dp_row((q & 3) + ((q >> 2) << 3) + (hl << 2));
#pragma unroll
      for (int s = 0; s < 2; ++s) {
        const int colb = (cb + s * 32 + l31) << 1;
#pragma unroll
        for (int q = 0; q < 16; ++q) {
          const float gi = acc[0][s][q] + biasv[0][s] + dpv[q] * wih2[0][s];
          const float gf = acc[1][s][q] + biasv[1][s] + dpv[q] * wih2[1][s];
          const float gg = acc[2][s][q] + biasv[2][s] + dpv[q] * wih2[2][s];
          const float go = acc[3][s][q] + biasv[3][s] + dpv[q] * wih2[3][s];
          float cv = (s == 0) ? c_reg0[q] : c_reg1[q];
          cv = fsig(gf) * cv + fsig(gi) * ftanh(gg);
          const float hv = fsig(go) * ftanh(cv);
          if (s == 0) c_reg0[q] = cv; else c_reg1[q] = cv;
          const int r = (q & 3) + ((q >> 2) << 3) + (hl << 2);
          *(unsigned short*)((char*)hAq + (r << 10) + (colb ^ (r << 4))) = f2bf(hv);
        }
      }
    }

    __syncthreads();  // single barrier: hA[p^1]/extA[p^1] complete for next step
    p ^= 1;
  }
}

extern "C" void kernel_launch(void* const* d_in, const int* in_sizes, int n_in,
                              void* d_out, int out_size, void* d_ws, size_t ws_size,
                              hipStream_t stream) {
  const float* noise   = (const float*)d_in[0];
  const float* cluster = (const float*)d_in[1];
  const float* gap     = (const float*)d_in[2];
  const float* Wih     = (const float*)d_in[3];
  const float* Whh     = (const float*)d_in[4];
  const float* bih     = (const float*)d_in[5];
  const float* bhh     = (const float*)d_in[6];
  const float* W1      = (const float*)d_in[7];
  const float* b1      = (const float*)d_in[8];
  const float* W2      = (const float*)d_in[9];
  const float* b2      = (const float*)d_in[10];

  unsigned short* us = (unsigned short*)d_ws;  // 3.03 MB packed stream

  prep_pack<<<(STREAM_SHORTS / 8 + 255) / 256, 256, 0, stream>>>(Wih, Whh, W1, us);
  lstm_seq<<<NBLK, NTHREADS, 0, stream>>>(noise, cluster, gap, Wih, bih, bhh, b1, W2, b2,
                                          us, (float*)d_out);
}